// Round 11
// baseline (201.167 us; speedup 1.0000x reference)
//
#include <hip/hip_runtime.h>
#include <cstddef>
#include <cstdint>

typedef float f4 __attribute__((ext_vector_type(4)));
typedef unsigned short us4 __attribute__((ext_vector_type(4)));
typedef short s8v __attribute__((ext_vector_type(8)));

#define HID 64
#define EPB 4096    // edges per partition block
#define CAP2 16384  // slots per 512-col bucket in partition buffer

// ---------------- bf16 helpers (RNE) ----------------
__device__ inline float b2f(unsigned short u) {
    union { unsigned u32; float f; } x; x.u32 = (unsigned)u << 16; return x.f;
}
__device__ inline unsigned short f2b(float f) {
    union { float f; unsigned u; } x; x.f = f;
    unsigned r = 0x7FFFu + ((x.u >> 16) & 1u);
    return (unsigned short)((x.u + r) >> 16);
}
__device__ inline f4 b2f4(us4 h) { f4 r; r[0]=b2f(h[0]); r[1]=b2f(h[1]); r[2]=b2f(h[2]); r[3]=b2f(h[3]); return r; }
__device__ inline us4 f2b4(f4 v) { us4 r; r[0]=f2b(v[0]); r[1]=f2b(v[1]); r[2]=f2b(v[2]); r[3]=f2b(v[3]); return r; }

__device__ inline f4 ld4(const float* p) { return *(const f4*)p; }
__device__ inline f4 ld4(const unsigned short* p) { return b2f4(*(const us4*)p); }
__device__ inline void st4(float* p, f4 v) { *(f4*)p = v; }
__device__ inline void st4(unsigned short* p, f4 v) { *(us4*)p = f2b4(v); }

// ---------------- init bucket cursors: gcur[b] = b*CAP2 ----------------
__global__ __launch_bounds__(256) void k_initcur(int* gcur) {
    int i = blockIdx.x * 256 + threadIdx.x;
    if (i < 512) gcur[i] = i * CAP2;
}

// ---------------- LDS-staged partition into 512-col buckets ----------------
// packed u32 = (col & 511) << 17 | row  (requires row < 2^17, E % 4 == 0)
__global__ __launch_bounds__(512) void k_partB(const int* __restrict__ row,
                                               const int* __restrict__ col,
                                               int* __restrict__ gcur,
                                               unsigned* __restrict__ buf, int E) {
    __shared__ int h[512];
    __shared__ int lo[512];
    __shared__ int lb[512];
    __shared__ int lcur[512];
    __shared__ unsigned lbuf[EPB];
    __shared__ unsigned short bk[EPB];
    int t = threadIdx.x;
    h[t] = 0;
    __syncthreads();
    int e0 = blockIdx.x * EPB, e1 = min(E, e0 + EPB);
    for (int i = e0 + t * 4; i < e1; i += 2048) {
        int4 c = *(const int4*)(col + i);
        atomicAdd(&h[c.x >> 9], 1);
        atomicAdd(&h[c.y >> 9], 1);
        atomicAdd(&h[c.z >> 9], 1);
        atomicAdd(&h[c.w >> 9], 1);
    }
    __syncthreads();
    int v = h[t];
    lo[t] = v;
    __syncthreads();
    for (int o = 1; o < 512; o <<= 1) {
        int x = (t >= o) ? lo[t - o] : 0;
        __syncthreads();
        lo[t] += x;
        __syncthreads();
    }
    int excl = lo[t] - v;
    lb[t] = v ? atomicAdd(&gcur[t], v) : 0;
    __syncthreads();
    lo[t] = excl;
    lcur[t] = excl;
    __syncthreads();
    for (int i = e0 + t * 4; i < e1; i += 2048) {
        int4 c = *(const int4*)(col + i);
        int4 r = *(const int4*)(row + i);
        int b0 = c.x >> 9; int p0 = atomicAdd(&lcur[b0], 1);
        lbuf[p0] = ((unsigned)(c.x & 511) << 17) | (unsigned)r.x; bk[p0] = (unsigned short)b0;
        int b1 = c.y >> 9; int p1 = atomicAdd(&lcur[b1], 1);
        lbuf[p1] = ((unsigned)(c.y & 511) << 17) | (unsigned)r.y; bk[p1] = (unsigned short)b1;
        int b2 = c.z >> 9; int p2 = atomicAdd(&lcur[b2], 1);
        lbuf[p2] = ((unsigned)(c.z & 511) << 17) | (unsigned)r.z; bk[p2] = (unsigned short)b2;
        int b3 = c.w >> 9; int p3 = atomicAdd(&lcur[b3], 1);
        lbuf[p3] = ((unsigned)(c.w & 511) << 17) | (unsigned)r.w; bk[p3] = (unsigned short)b3;
    }
    __syncthreads();
    int n = e1 - e0;
    for (int i = t; i < n; i += 512) {
        int b = bk[i];
        buf[lb[b] + (i - lo[b])] = lbuf[i];
    }
}

// ---------------- scan bucket counts (from gcur) -> gbase ----------------
__global__ __launch_bounds__(512) void k_scanB(const int* __restrict__ gcur,
                                               int* __restrict__ gbase, int NB, int E) {
    __shared__ int s[512];
    int t = threadIdx.x;
    int v = (t < NB) ? (gcur[t] - t * CAP2) : 0;
    s[t] = v;
    __syncthreads();
    for (int o = 1; o < 512; o <<= 1) {
        int x = (t >= o) ? s[t - o] : 0;
        __syncthreads();
        s[t] += x;
        __syncthreads();
    }
    if (t < NB) gbase[t] = s[t] - v;
    if (t == 0) gbase[NB] = E;
}

// ---------------- pass C: per-bucket CSR finish, (node, src>>12)-sorted ----------------
// Sorting each node's list by source tile (4096-node bands) makes the gather's
// concurrent source reads L2-banded instead of random over the full g array.
__global__ __launch_bounds__(512) void k_passC(const unsigned* __restrict__ buf,
                                               const int* __restrict__ gcur,
                                               const int* __restrict__ gbase,
                                               int* __restrict__ rowptr,
                                               int* __restrict__ srcs,
                                               float* __restrict__ dis, int N, int E) {
    __shared__ unsigned sbuf[CAP2];   // 64 KB
    __shared__ int hist[16384];       // 64 KB: 512 nodes x 32 src-tiles; reused as cursors
    __shared__ int ssc[512];
    int b = blockIdx.x, t = threadIdx.x;
    int r0 = b * CAP2, r1 = gcur[b];
    int n = r1 - r0;
    int w0 = gbase[b];

    for (int i = t; i < 16384; i += 512) hist[i] = 0;
    __syncthreads();
    for (int i = r0 + t; i < r1; i += 512) {
        unsigned u = buf[i];
        int key = (int)((u >> 17) & 511) * 32 + (int)((u & 0x1FFFF) >> 12);
        atomicAdd(&hist[key], 1);
    }
    __syncthreads();

    // thread t owns node t: sequential exclusive prefix over its 32 tile-bins
    int base = t * 32;
    int local[32];
    int deg = 0;
    #pragma unroll
    for (int j = 0; j < 32; ++j) { local[j] = deg; deg += hist[base + j]; }
    ssc[t] = deg;
    __syncthreads();
    for (int o = 1; o < 512; o <<= 1) {
        int x = (t >= o) ? ssc[t - o] : 0;
        __syncthreads();
        ssc[t] += x;
        __syncthreads();
    }
    int excl = ssc[t] - deg;    // node-level exclusive prefix within bucket

    int gc = b * 512 + t;
    if (gc < N) {
        rowptr[gc] = w0 + excl;
        dis[gc] = rsqrtf(1.0f + (float)deg);
    }
    if (b == (int)gridDim.x - 1 && t == 0) rowptr[N] = E;

    // write back per-key cursors
    #pragma unroll
    for (int j = 0; j < 32; ++j) hist[base + j] = excl + local[j];
    __syncthreads();

    for (int i = r0 + t; i < r1; i += 512) {
        unsigned u = buf[i];
        int key = (int)((u >> 17) & 511) * 32 + (int)((u & 0x1FFFF) >> 12);
        int pos = atomicAdd(&hist[key], 1);
        sbuf[pos] = u & 0x1FFFF;
    }
    __syncthreads();
    for (int i = t; i < n; i += 512) srcs[w0 + i] = (int)sbuf[i];
}

// ---------------- MFMA GEMM: 64 rows x NC cols, K in {64,128} ----------------
template<int K, int NC, typename TIN>
__global__ __launch_bounds__(256) void k_gemmM(
    const TIN* __restrict__ X, const float* __restrict__ W,
    const float* __restrict__ bias, const float* __restrict__ scale,
    unsigned short* __restrict__ outA, unsigned short* __restrict__ outB, int N)
{
    constexpr int KP = K + 8;
    __shared__ unsigned short xs[64][KP];
    __shared__ unsigned short wt[NC][KP];
    const int t = threadIdx.x;
    const int lane = t & 63;
    const int wv = t >> 6;
    const int nbase = blockIdx.x * 64;

    if constexpr (sizeof(TIN) == 4) {
        for (int idx = t; idx < 64 * K / 4; idx += 256) {
            int row = idx / (K / 4);
            int kc = (idx % (K / 4)) * 4;
            int g = nbase + row;
            f4 v = {0.f, 0.f, 0.f, 0.f};
            if (g < N) v = *(const f4*)((const float*)X + (size_t)g * K + kc);
            *(us4*)&xs[row][kc] = f2b4(v);
        }
    } else {
        for (int idx = t; idx < 64 * K / 8; idx += 256) {
            int row = idx / (K / 8);
            int kc = (idx % (K / 8)) * 8;
            int g = nbase + row;
            uint4 v = {0u, 0u, 0u, 0u};
            if (g < N) v = *(const uint4*)((const unsigned short*)X + (size_t)g * K + kc);
            *(uint4*)&xs[row][kc] = v;
        }
    }
    constexpr int WROWS = K * NC / 64;
    for (int idx = t; idx < WROWS * 16; idx += 256) {
        int ks = idx >> 4;
        int c4 = (idx & 15) * 4;
        f4 v = *(const f4*)(W + (size_t)ks * 64 + c4);
        int cofs = (NC == 128 && ks >= K) ? 64 : 0;
        int kk = ks & (K - 1);
        #pragma unroll
        for (int j = 0; j < 4; ++j)
            wt[c4 + j + cofs][kk] = f2b(v[j]);
    }
    __syncthreads();

    constexpr int NT = NC / 16;
    f4 acc[NT];
    #pragma unroll
    for (int i = 0; i < NT; ++i) acc[i] = (f4){0.f, 0.f, 0.f, 0.f};

    const int l15 = lane & 15;
    const int kbase = (lane >> 4) * 8;
    #pragma unroll
    for (int kt = 0; kt < K / 32; ++kt) {
        s8v a = *(const s8v*)&xs[wv * 16 + l15][kt * 32 + kbase];
        #pragma unroll
        for (int ct = 0; ct < NT; ++ct) {
            s8v b = *(const s8v*)&wt[ct * 16 + l15][kt * 32 + kbase];
            acc[ct] = __builtin_amdgcn_mfma_f32_16x16x32_bf16(a, b, acc[ct], 0, 0, 0);
        }
    }

    const int r0 = (lane >> 4) * 4;
    #pragma unroll
    for (int r = 0; r < 4; ++r) {
        int g = nbase + wv * 16 + r0 + r;
        if (g >= N) continue;
        float sc = scale ? scale[g] : 1.0f;
        #pragma unroll
        for (int ct = 0; ct < NT; ++ct) {
            int c = ct * 16 + l15;
            float v = acc[ct][r] * sc;
            if (c < 64) {
                if (bias) v += bias[c];
                outA[(size_t)g * 64 + c] = f2b(v);
            } else {
                outB[(size_t)g * 64 + (c - 64)] = f2b(v);
            }
        }
    }
}

// ---------------- gather (bf16 in/out, fp32 accum, 4-deep MLP) ----------------
__global__ __launch_bounds__(256) void k_gather(
    const unsigned short* __restrict__ g, const int* __restrict__ rowptr,
    const int* __restrict__ srcs, const float* __restrict__ dis,
    const float* __restrict__ bias, unsigned short* __restrict__ out, int N, int do_relu)
{
    int t = blockIdx.x * 256 + threadIdx.x;
    int node = t >> 4;
    if (node >= N) return;
    int c4 = (t & 15) * 4;

    f4 a0 = ld4(g + (size_t)node * HID + c4);   // self-loop
    f4 a1 = {0.f, 0.f, 0.f, 0.f};
    f4 a2 = {0.f, 0.f, 0.f, 0.f};
    f4 a3 = {0.f, 0.f, 0.f, 0.f};
    int s = rowptr[node], e = rowptr[node + 1];
    for (; s + 3 < e; s += 4) {
        int r0 = srcs[s], r1 = srcs[s + 1], r2 = srcs[s + 2], r3 = srcs[s + 3];
        a0 += ld4(g + (size_t)r0 * HID + c4);
        a1 += ld4(g + (size_t)r1 * HID + c4);
        a2 += ld4(g + (size_t)r2 * HID + c4);
        a3 += ld4(g + (size_t)r3 * HID + c4);
    }
    for (; s < e; ++s) a0 += ld4(g + (size_t)srcs[s] * HID + c4);
    a0 = (a0 + a1) + (a2 + a3);

    float sc = dis[node];
    f4 r;
    #pragma unroll
    for (int j = 0; j < 4; ++j) {
        r[j] = a0[j] * sc + bias[c4 + j];
        if (do_relu) r[j] = r[j] > 0.f ? r[j] : 0.f;
    }
    st4(out + (size_t)node * HID + c4, r);
}

// ---------------- fallback path kernels (fp32 VALU GEMM + atomic scatter) ----------------
template<int K, typename TIN, typename TOUT>
__global__ __launch_bounds__(256) void k_gemm(
    const TIN* __restrict__ X, const float* __restrict__ W,
    const float* __restrict__ bias, const float* __restrict__ scale,
    TOUT* __restrict__ out1, TOUT* __restrict__ out2, int N)
{
    __shared__ float xs[64][68];
    __shared__ float ws[64][64];
    const int t = threadIdx.x;
    const int nbase = blockIdx.x * 64;
    const int c4 = (t & 15) * 4;
    const int n4 = (t >> 4) * 4;

    float acc[4][4] = {{0.f,0.f,0.f,0.f},{0.f,0.f,0.f,0.f},{0.f,0.f,0.f,0.f},{0.f,0.f,0.f,0.f}};

    const int node = t & 63;
    const int gn = nbase + node;
    const TIN* Xrow = (gn < N) ? (X + (size_t)gn * K) : nullptr;
    const f4* W4 = (const f4*)W;

    for (int kt = 0; kt < K / 64; ++kt) {
        __syncthreads();
        #pragma unroll
        for (int i = 0; i < 4; ++i) {
            int k4r = i * 4 + (t >> 6);
            f4 v = {0.f, 0.f, 0.f, 0.f};
            if (Xrow) v = ld4(Xrow + (size_t)(kt * 16 + k4r) * 4);
            xs[k4r * 4 + 0][node] = v[0];
            xs[k4r * 4 + 1][node] = v[1];
            xs[k4r * 4 + 2][node] = v[2];
            xs[k4r * 4 + 3][node] = v[3];
        }
        #pragma unroll
        for (int i = 0; i < 4; ++i) {
            int f = i * 256 + t;
            int k = f >> 4, m4 = f & 15;
            *(f4*)&ws[k][m4 * 4] = W4[(size_t)(kt * 64 + k) * 16 + m4];
        }
        __syncthreads();
        #pragma unroll 8
        for (int k = 0; k < 64; ++k) {
            f4 xv = *(const f4*)&xs[k][n4];
            f4 wv = *(const f4*)&ws[k][c4];
            #pragma unroll
            for (int i2 = 0; i2 < 4; ++i2)
                #pragma unroll
                for (int j = 0; j < 4; ++j)
                    acc[i2][j] += xv[i2] * wv[j];
        }
    }

    #pragma unroll
    for (int i = 0; i < 4; ++i) {
        int g = nbase + n4 + i;
        if (g < N) {
            float s = scale ? scale[g] : 1.0f;
            f4 r;
            #pragma unroll
            for (int j = 0; j < 4; ++j) {
                float b = bias ? bias[c4 + j] : 0.0f;
                r[j] = acc[i][j] * s + b;
            }
            st4(out1 + (size_t)g * HID + c4, r);
            if (out2) st4(out2 + (size_t)g * HID + c4, r);
        }
    }
}

template<typename TIN>
__global__ __launch_bounds__(256) void k_gemm2(
    const TIN* __restrict__ X, const float* __restrict__ W,
    const float* __restrict__ bias,
    unsigned short* __restrict__ outA, unsigned short* __restrict__ outB, int N)
{
    __shared__ float xs[64][68];
    __shared__ float ws[64][128];
    const int t = threadIdx.x;
    const int nbase = blockIdx.x * 64;
    const int c4 = (t & 15) * 4;
    const int n4 = (t >> 4) * 4;

    float accA[4][4] = {{0.f,0.f,0.f,0.f},{0.f,0.f,0.f,0.f},{0.f,0.f,0.f,0.f},{0.f,0.f,0.f,0.f}};
    float accB[4][4] = {{0.f,0.f,0.f,0.f},{0.f,0.f,0.f,0.f},{0.f,0.f,0.f,0.f},{0.f,0.f,0.f,0.f}};

    const int node = t & 63;
    const int gn = nbase + node;
    const TIN* Xrow = (gn < N) ? (X + (size_t)gn * HID) : nullptr;
    const f4* W4 = (const f4*)W;

    #pragma unroll
    for (int i = 0; i < 4; ++i) {
        int k4r = i * 4 + (t >> 6);
        f4 v = {0.f, 0.f, 0.f, 0.f};
        if (Xrow) v = ld4(Xrow + (size_t)k4r * 4);
        xs[k4r * 4 + 0][node] = v[0];
        xs[k4r * 4 + 1][node] = v[1];
        xs[k4r * 4 + 2][node] = v[2];
        xs[k4r * 4 + 3][node] = v[3];
    }
    #pragma unroll
    for (int i = 0; i < 8; ++i) {
        int f = i * 256 + t;
        int r = f >> 4, m4 = f & 15;
        int k = r & 63, half = (r >> 6) * 64;
        *(f4*)&ws[k][half + m4 * 4] = W4[f];
    }
    __syncthreads();
    #pragma unroll 8
    for (int k = 0; k < 64; ++k) {
        f4 xv = *(const f4*)&xs[k][n4];
        f4 wa = *(const f4*)&ws[k][c4];
        f4 wb = *(const f4*)&ws[k][64 + c4];
        #pragma unroll
        for (int i2 = 0; i2 < 4; ++i2)
            #pragma unroll
            for (int j = 0; j < 4; ++j) {
                accA[i2][j] += xv[i2] * wa[j];
                accB[i2][j] += xv[i2] * wb[j];
            }
    }

    #pragma unroll
    for (int i = 0; i < 4; ++i) {
        int g = nbase + n4 + i;
        if (g < N) {
            f4 ra, rb;
            #pragma unroll
            for (int j = 0; j < 4; ++j) {
                ra[j] = accA[i][j] + bias[c4 + j];
                rb[j] = accB[i][j];
            }
            st4(outA + (size_t)g * HID + c4, ra);
            st4(outB + (size_t)g * HID + c4, rb);
        }
    }
}

__global__ __launch_bounds__(256) void k_count(const int* __restrict__ col,
                                               float* __restrict__ deg, int E) {
    int e = blockIdx.x * 256 + threadIdx.x;
    if (e < E) unsafeAtomicAdd(&deg[col[e]], 1.0f);
}
__global__ __launch_bounds__(256) void k_initf(float* p, float v, int n) {
    int i = blockIdx.x * 256 + threadIdx.x;
    if (i < n) p[i] = v;
}
__global__ __launch_bounds__(256) void k_rsqrt(float* deg, int N) {
    int i = blockIdx.x * 256 + threadIdx.x;
    if (i < N) deg[i] = rsqrtf(deg[i]);
}
__global__ __launch_bounds__(256) void k_scatter(
    const float* __restrict__ g, const int* __restrict__ row, const int* __restrict__ col,
    float* __restrict__ acc, int E)
{
    int t = blockIdx.x * 256 + threadIdx.x;
    int e = t >> 4;
    if (e >= E) return;
    int c4 = (t & 15) * 4;
    int r = row[e], c = col[e];
    f4 v = *(const f4*)(g + (size_t)r * HID + c4);
    float* dst = acc + (size_t)c * HID + c4;
    unsafeAtomicAdd(dst + 0, v[0]);
    unsafeAtomicAdd(dst + 1, v[1]);
    unsafeAtomicAdd(dst + 2, v[2]);
    unsafeAtomicAdd(dst + 3, v[3]);
}
__global__ __launch_bounds__(256) void k_finish(
    const float* __restrict__ acc, const float* __restrict__ dis, const float* __restrict__ bias,
    float* __restrict__ out, int N, int do_relu)
{
    int t = blockIdx.x * 256 + threadIdx.x;
    if (t >= N * 16) return;
    int node = t >> 4, c4 = (t & 15) * 4;
    float s = dis[node];
    f4 v = *(const f4*)(acc + (size_t)t * 4);
    f4 r;
    #pragma unroll
    for (int j = 0; j < 4; ++j) {
        r[j] = v[j] * s + bias[c4 + j];
        if (do_relu) r[j] = r[j] > 0.f ? r[j] : 0.f;
    }
    *(f4*)(out + (size_t)t * 4) = r;
}

// ---------------- pair scorer: 16 lanes per 2 pairs, 4 row loads in flight ----------------
__global__ __launch_bounds__(256) void k_pair(
    const unsigned short* __restrict__ A, const unsigned short* __restrict__ B,
    const int* __restrict__ pairs, const float* __restrict__ w2, const float* __restrict__ b2,
    float* __restrict__ out, int P)
{
    __shared__ float w2s[64];
    if (threadIdx.x < 64) w2s[threadIdx.x] = w2[threadIdx.x];
    __syncthreads();
    int gidx = blockIdx.x * 256 + threadIdx.x;
    int grp = gidx >> 4;
    int p0 = grp * 2, p1 = p0 + 1;
    if (p0 >= P) return;
    int l = gidx & 15;
    int sub = l & 7;
    int isB = l >> 3;
    const unsigned short* base = isB ? B : A;
    const int* pp = isB ? (pairs + P) : pairs;

    int n0 = pp[p0];
    int4 o0 = *(const int4*)(base + (size_t)n0 * HID + sub * 8);
    bool has1 = (p1 < P);
    int4 o1 = {0, 0, 0, 0};
    if (has1) {
        int n1 = pp[p1];
        o1 = *(const int4*)(base + (size_t)n1 * HID + sub * 8);
    }

    int4 q0, q1;
    q0.x = __shfl_xor(o0.x, 8, 16); q0.y = __shfl_xor(o0.y, 8, 16);
    q0.z = __shfl_xor(o0.z, 8, 16); q0.w = __shfl_xor(o0.w, 8, 16);
    q1.x = __shfl_xor(o1.x, 8, 16); q1.y = __shfl_xor(o1.y, 8, 16);
    q1.z = __shfl_xor(o1.z, 8, 16); q1.w = __shfl_xor(o1.w, 8, 16);

    const float* wv = &w2s[sub * 8];
    int oa0[4] = {o0.x, o0.y, o0.z, o0.w};
    int ob0[4] = {q0.x, q0.y, q0.z, q0.w};
    int oa1[4] = {o1.x, o1.y, o1.z, o1.w};
    int ob1[4] = {q1.x, q1.y, q1.z, q1.w};
    float acc0 = 0.f, acc1 = 0.f;
    #pragma unroll
    for (int k = 0; k < 4; ++k) {
        float alo = __uint_as_float((unsigned)oa0[k] << 16);
        float ahi = __uint_as_float((unsigned)oa0[k] & 0xFFFF0000u);
        float blo = __uint_as_float((unsigned)ob0[k] << 16);
        float bhi = __uint_as_float((unsigned)ob0[k] & 0xFFFF0000u);
        float zlo = alo + blo; zlo = zlo > 0.f ? zlo : 0.f;
        float zhi = ahi + bhi; zhi = zhi > 0.f ? zhi : 0.f;
        acc0 += zlo * wv[2 * k] + zhi * wv[2 * k + 1];

        float clo = __uint_as_float((unsigned)oa1[k] << 16);
        float chi = __uint_as_float((unsigned)oa1[k] & 0xFFFF0000u);
        float dlo = __uint_as_float((unsigned)ob1[k] << 16);
        float dhi = __uint_as_float((unsigned)ob1[k] & 0xFFFF0000u);
        float ylo = clo + dlo; ylo = ylo > 0.f ? ylo : 0.f;
        float yhi = chi + dhi; yhi = yhi > 0.f ? yhi : 0.f;
        acc1 += ylo * wv[2 * k] + yhi * wv[2 * k + 1];
    }
    acc0 += __shfl_xor(acc0, 1, 16);
    acc0 += __shfl_xor(acc0, 2, 16);
    acc0 += __shfl_xor(acc0, 4, 16);
    acc1 += __shfl_xor(acc1, 1, 16);
    acc1 += __shfl_xor(acc1, 2, 16);
    acc1 += __shfl_xor(acc1, 4, 16);
    if (l == 0) {
        float bb = b2[0];
        out[p0] = 1.0f / (1.0f + __expf(-(acc0 + bb)));
        if (has1) out[p1] = 1.0f / (1.0f + __expf(-(acc1 + bb)));
    }
}

extern "C" void kernel_launch(void* const* d_in, const int* in_sizes, int n_in,
                              void* d_out, int out_size, void* d_ws, size_t ws_size,
                              hipStream_t stream)
{
    if (n_in < 11) return;
    const float* x    = (const float*)d_in[0];
    const int*   ei   = (const int*)d_in[1];
    const int*   ep   = (const int*)d_in[2];
    const float* W1   = (const float*)d_in[3];
    const float* b1   = (const float*)d_in[4];
    const float* W2   = (const float*)d_in[5];
    const float* b2   = (const float*)d_in[6];
    const float* lpW1 = (const float*)d_in[7];
    const float* lpb1 = (const float*)d_in[8];
    const float* lpW2 = (const float*)d_in[9];
    const float* lpb2 = (const float*)d_in[10];
    const int N = in_sizes[0] / 128;
    const int E = in_sizes[1] / 2;
    const int P = in_sizes[2] / 2;
    const int* erow = ei;
    const int* ecol = ei + E;
    float* out = (float*)d_out;

    const int gb  = (N + 63) / 64;
    const int hb  = (N * 16 + 255) / 256;
    const int NB2 = (N + 511) / 512;
    const int pa  = (E + EPB - 1) / EPB;
    const int pb  = (int)(((size_t)((P + 1) / 2) * 16 + 255) / 256);

    // ---- workspace layout ----
    char* w = (char*)d_ws;
    float* dis    = (float*)w;  w += (size_t)N * 4;
    int*   rowptr = (int*)w;    w += ((size_t)N + 1) * 4;
    int*   gbase  = (int*)w;    w += 513 * 4;
    int*   gcur   = (int*)w;    w += 512 * 4;
    int*   srcs   = (int*)w;    w += (size_t)E * 4;
    size_t off = ((size_t)(w - (char*)d_ws) + 255) & ~(size_t)255;

    size_t featB = (size_t)N * HID * 2;
    unsigned short* bufA = (unsigned short*)((char*)d_ws + off);
    unsigned short* bufB = bufA + (size_t)N * HID;
    size_t need = off + 2 * featB;

    bool useNew = (N <= 131072) && (NB2 <= 512) && (ws_size >= need) &&
                  ((size_t)E <= 20 * (size_t)N) && (E % 4 == 0) &&
                  ((size_t)NB2 * CAP2 * 4 <= 2 * featB);

    if (useNew) {
        unsigned* pbuf = (unsigned*)bufA;   // aliases bufA/bufB (dead until GEMM1)

        // ---- CSR build (destination buckets, source-tile-sorted lists) ----
        k_initcur<<<2, 256, 0, stream>>>(gcur);
        k_partB<<<pa, 512, 0, stream>>>(erow, ecol, gcur, pbuf, E);
        k_scanB<<<1, 512, 0, stream>>>(gcur, gbase, NB2, E);
        k_passC<<<NB2, 512, 0, stream>>>(pbuf, gcur, gbase, rowptr, srcs, dis, N, E);

        // ---- layer 1 (MFMA) ----
        k_gemmM<128, 64, float><<<gb, 256, 0, stream>>>(x, W1, nullptr, dis, bufA, nullptr, N);
        k_gather<<<hb, 256, 0, stream>>>(bufA, rowptr, srcs, dis, b1, bufB, N, 1);
        // ---- layer 2 (MFMA) ----
        k_gemmM<64, 64, unsigned short><<<gb, 256, 0, stream>>>(bufB, W2, nullptr, dis, bufA, nullptr, N);
        k_gather<<<hb, 256, 0, stream>>>(bufA, rowptr, srcs, dis, b2, bufB, N, 0);
        // ---- fused link-pred projections (MFMA, dual-output, in-place safe) ----
        k_gemmM<64, 128, unsigned short><<<gb, 256, 0, stream>>>(bufB, lpW1, lpb1, nullptr, bufA, bufB, N);

        k_pair<<<pb, 256, 0, stream>>>(bufA, bufB, ep, lpW2, lpb2, out, P);
    } else {
        // ---- fallback: fp32 VALU + atomic scatter ----
        size_t off_fb = (((size_t)N + 512) * 4 + 255) & ~(size_t)255;
        float* fA = (float*)((char*)d_ws + off_fb);
        float* fB = fA + (size_t)N * HID;
        if (ws_size < off_fb + 2 * (size_t)N * HID * 4) return;
        const int nb = (N + 255) / 256;
        const int eb = (E + 255) / 256;
        const int sb = (int)(((size_t)E * 16 + 255) / 256);
        k_initf<<<nb, 256, 0, stream>>>(dis, 1.0f, N);
        k_count<<<eb, 256, 0, stream>>>(ecol, dis, E);
        k_rsqrt<<<nb, 256, 0, stream>>>(dis, N);
        k_gemm<128, float, float><<<gb, 256, 0, stream>>>(x, W1, nullptr, dis, fA, fB, N);
        k_scatter<<<sb, 256, 0, stream>>>(fA, erow, ecol, fB, E);
        k_finish<<<hb, 256, 0, stream>>>(fB, dis, b1, fB, N, 1);
        k_gemm<64, float, float><<<gb, 256, 0, stream>>>(fB, W2, nullptr, dis, fA, fB, N);
        k_scatter<<<sb, 256, 0, stream>>>(fA, erow, ecol, fB, E);
        k_finish<<<hb, 256, 0, stream>>>(fB, dis, b2, fB, N, 0);
        unsigned short* bA = (unsigned short*)fA;
        unsigned short* bB = bA + (size_t)N * HID;
        k_gemm2<float><<<gb, 256, 0, stream>>>(fB, lpW1, lpb1, bA, bB, N);
        k_pair<<<pb, 256, 0, stream>>>(bA, bB, ep, lpW2, lpb2, out, P);
    }
}

// Round 12
// 175.439 us; speedup vs baseline: 1.1466x; 1.1466x over previous
//
#include <hip/hip_runtime.h>
#include <cstddef>
#include <cstdint>

typedef float f4 __attribute__((ext_vector_type(4)));
typedef unsigned short us4 __attribute__((ext_vector_type(4)));
typedef short s8v __attribute__((ext_vector_type(8)));

#define HID 64
#define EPB 4096    // edges per partition block
#define CAP2 16384  // slots per 512-col bucket in partition buffer
#define SMEM_BYTES 52224   // max(partition 32KB, gemm 128x136 + 64x136 bf16)

// ---------------- bf16 helpers (RNE) ----------------
__device__ inline float b2f(unsigned short u) {
    union { unsigned u32; float f; } x; x.u32 = (unsigned)u << 16; return x.f;
}
__device__ inline unsigned short f2b(float f) {
    union { float f; unsigned u; } x; x.f = f;
    unsigned r = 0x7FFFu + ((x.u >> 16) & 1u);
    return (unsigned short)((x.u + r) >> 16);
}
__device__ inline f4 b2f4(us4 h) { f4 r; r[0]=b2f(h[0]); r[1]=b2f(h[1]); r[2]=b2f(h[2]); r[3]=b2f(h[3]); return r; }
__device__ inline us4 f2b4(f4 v) { us4 r; r[0]=f2b(v[0]); r[1]=f2b(v[1]); r[2]=f2b(v[2]); r[3]=f2b(v[3]); return r; }

__device__ inline f4 ld4(const float* p) { return *(const f4*)p; }
__device__ inline f4 ld4(const unsigned short* p) { return b2f4(*(const us4*)p); }
__device__ inline void st4(float* p, f4 v) { *(f4*)p = v; }
__device__ inline void st4(unsigned short* p, f4 v) { *(us4*)p = f2b4(v); }

// ---------------- init bucket cursors: gcur[b] = b*CAP2 ----------------
__global__ __launch_bounds__(256) void k_initcur(int* gcur) {
    int i = blockIdx.x * 256 + threadIdx.x;
    if (i < 512) gcur[i] = i * CAP2;
}

// ---------------- fused: [blocks < PA] LDS-staged partition  |  [rest] GEMM1 x@W1 ----------------
// partition: packed u32 = (col & 511) << 17 | row  (requires row < 2^17, E % 4 == 0)
// gemm: 128 rows x 64 cols, K=128, bf16 MFMA, raw product (no scale/bias)
__global__ __launch_bounds__(512) void k_fused1(
    const int* __restrict__ row, const int* __restrict__ col,
    int* __restrict__ gcur, unsigned* __restrict__ buf, int E,
    const float* __restrict__ X, const float* __restrict__ W,
    unsigned short* __restrict__ outA, int N, int PA)
{
    __shared__ __align__(16) char smem[SMEM_BYTES];
    const int t = threadIdx.x;

    if ((int)blockIdx.x < PA) {
        // ================= partition mode (32 KB of smem) =================
        int* h    = (int*)smem;            // 512
        int* lo   = h + 512;               // 512
        int* lb   = lo + 512;              // 512
        int* lcur = lb + 512;              // 512
        unsigned* lbuf = (unsigned*)(smem + 8192);            // EPB u32 = 16 KB
        unsigned short* bk = (unsigned short*)(smem + 24576); // EPB u16 = 8 KB

        h[t] = 0;
        __syncthreads();
        int e0 = blockIdx.x * EPB, e1 = min(E, e0 + EPB);
        for (int i = e0 + t * 4; i < e1; i += 2048) {
            int4 c = *(const int4*)(col + i);
            atomicAdd(&h[c.x >> 9], 1);
            atomicAdd(&h[c.y >> 9], 1);
            atomicAdd(&h[c.z >> 9], 1);
            atomicAdd(&h[c.w >> 9], 1);
        }
        __syncthreads();
        int v = h[t];
        lo[t] = v;
        __syncthreads();
        for (int o = 1; o < 512; o <<= 1) {
            int x2 = (t >= o) ? lo[t - o] : 0;
            __syncthreads();
            lo[t] += x2;
            __syncthreads();
        }
        int excl = lo[t] - v;
        lb[t] = v ? atomicAdd(&gcur[t], v) : 0;
        __syncthreads();
        lo[t] = excl;
        lcur[t] = excl;
        __syncthreads();
        for (int i = e0 + t * 4; i < e1; i += 2048) {
            int4 c = *(const int4*)(col + i);
            int4 r = *(const int4*)(row + i);
            int b0 = c.x >> 9; int p0 = atomicAdd(&lcur[b0], 1);
            lbuf[p0] = ((unsigned)(c.x & 511) << 17) | (unsigned)r.x; bk[p0] = (unsigned short)b0;
            int b1 = c.y >> 9; int p1 = atomicAdd(&lcur[b1], 1);
            lbuf[p1] = ((unsigned)(c.y & 511) << 17) | (unsigned)r.y; bk[p1] = (unsigned short)b1;
            int b2 = c.z >> 9; int p2 = atomicAdd(&lcur[b2], 1);
            lbuf[p2] = ((unsigned)(c.z & 511) << 17) | (unsigned)r.z; bk[p2] = (unsigned short)b2;
            int b3 = c.w >> 9; int p3 = atomicAdd(&lcur[b3], 1);
            lbuf[p3] = ((unsigned)(c.w & 511) << 17) | (unsigned)r.w; bk[p3] = (unsigned short)b3;
        }
        __syncthreads();
        int n = e1 - e0;
        for (int i = t; i < n; i += 512) {
            int b = bk[i];
            buf[lb[b] + (i - lo[b])] = lbuf[i];
        }
    } else {
        // ================= gemm1 mode: 128 rows, K=128, NC=64 =================
        constexpr int KP = 136;
        unsigned short* xs = (unsigned short*)smem;             // [128][136]
        unsigned short* wt = (unsigned short*)(smem + 34816);   // [64][136]
        const int nbase = ((int)blockIdx.x - PA) * 128;

        for (int idx = t; idx < 4096; idx += 512) {     // 128 rows x 32 f4
            int r = idx >> 5;
            int kc = (idx & 31) * 4;
            int g = nbase + r;
            f4 v = {0.f, 0.f, 0.f, 0.f};
            if (g < N) v = *(const f4*)(X + (size_t)g * 128 + kc);
            *(us4*)&xs[r * KP + kc] = f2b4(v);
        }
        for (int idx = t; idx < 2048; idx += 512) {     // 128 k-rows x 16 f4
            int ks = idx >> 4;
            int c4 = (idx & 15) * 4;
            f4 v = *(const f4*)(W + (size_t)ks * 64 + c4);
            #pragma unroll
            for (int j = 0; j < 4; ++j)
                wt[(c4 + j) * KP + ks] = f2b(v[j]);
        }
        __syncthreads();

        const int lane = t & 63;
        const int wv = t >> 6;
        const int l15 = lane & 15;
        const int kb = (lane >> 4) * 8;
        f4 acc[4];
        #pragma unroll
        for (int i = 0; i < 4; ++i) acc[i] = (f4){0.f, 0.f, 0.f, 0.f};
        #pragma unroll
        for (int kt = 0; kt < 4; ++kt) {
            s8v a = *(const s8v*)&xs[(wv * 16 + l15) * KP + kt * 32 + kb];
            #pragma unroll
            for (int ct = 0; ct < 4; ++ct) {
                s8v b = *(const s8v*)&wt[(ct * 16 + l15) * KP + kt * 32 + kb];
                acc[ct] = __builtin_amdgcn_mfma_f32_16x16x32_bf16(a, b, acc[ct], 0, 0, 0);
            }
        }
        const int r0 = (lane >> 4) * 4;
        #pragma unroll
        for (int r = 0; r < 4; ++r) {
            int g = nbase + wv * 16 + r0 + r;
            if (g >= N) continue;
            #pragma unroll
            for (int ct = 0; ct < 4; ++ct) {
                int c = ct * 16 + l15;
                outA[(size_t)g * 64 + c] = f2b(acc[ct][r]);
            }
        }
    }
}

// ---------------- pass C: per-bucket CSR finish (rowptr, dis, srcs); self-scans gbase ----------------
__global__ __launch_bounds__(512) void k_passC(const unsigned* __restrict__ buf,
                                               const int* __restrict__ gcur,
                                               int* __restrict__ rowptr,
                                               int* __restrict__ srcs,
                                               float* __restrict__ dis, int N, int E, int NB) {
    __shared__ unsigned sbuf[CAP2];
    __shared__ int hist[512];
    __shared__ int off[512];
    __shared__ int cur[512];
    int b = blockIdx.x, t = threadIdx.x;

    // block-local computation of w0 = sum of bucket counts below b
    int c0 = (t < NB) ? (gcur[t] - t * CAP2) : 0;
    off[t] = c0;
    __syncthreads();
    for (int o = 1; o < 512; o <<= 1) {
        int x = (t >= o) ? off[t - o] : 0;
        __syncthreads();
        off[t] += x;
        __syncthreads();
    }
    int w0 = (b == 0) ? 0 : off[b - 1];
    if (b == 0 && t == 0) rowptr[N] = E;
    __syncthreads();

    int r0 = b * CAP2, r1 = gcur[b];
    int n = r1 - r0;
    hist[t] = 0;
    __syncthreads();
    for (int i = r0 + t; i < r1; i += 512) atomicAdd(&hist[(buf[i] >> 17) & 511], 1);
    __syncthreads();
    int v = hist[t];
    off[t] = v;
    __syncthreads();
    for (int o = 1; o < 512; o <<= 1) {
        int x = (t >= o) ? off[t - o] : 0;
        __syncthreads();
        off[t] += x;
        __syncthreads();
    }
    int excl = off[t] - v;
    int gc = b * 512 + t;
    if (gc < N) {
        rowptr[gc] = w0 + excl;
        dis[gc] = rsqrtf(1.0f + (float)v);
    }
    cur[t] = excl;
    __syncthreads();
    for (int i = r0 + t; i < r1; i += 512) {
        unsigned u = buf[i];
        int pos = atomicAdd(&cur[(u >> 17) & 511], 1);
        sbuf[pos] = u & 0x1FFFF;
    }
    __syncthreads();
    for (int i = t; i < n; i += 512) srcs[w0 + i] = (int)sbuf[i];
}

// ---------------- MFMA GEMM: 64 rows x NC cols, K in {64,128} ----------------
template<int K, int NC, typename TIN>
__global__ __launch_bounds__(256) void k_gemmM(
    const TIN* __restrict__ X, const float* __restrict__ W,
    const float* __restrict__ bias, const float* __restrict__ scale,
    unsigned short* __restrict__ outA, unsigned short* __restrict__ outB, int N)
{
    constexpr int KP = K + 8;
    __shared__ unsigned short xs[64][KP];
    __shared__ unsigned short wt[NC][KP];
    const int t = threadIdx.x;
    const int lane = t & 63;
    const int wv = t >> 6;
    const int nbase = blockIdx.x * 64;

    if constexpr (sizeof(TIN) == 4) {
        for (int idx = t; idx < 64 * K / 4; idx += 256) {
            int row = idx / (K / 4);
            int kc = (idx % (K / 4)) * 4;
            int g = nbase + row;
            f4 v = {0.f, 0.f, 0.f, 0.f};
            if (g < N) v = *(const f4*)((const float*)X + (size_t)g * K + kc);
            *(us4*)&xs[row][kc] = f2b4(v);
        }
    } else {
        for (int idx = t; idx < 64 * K / 8; idx += 256) {
            int row = idx / (K / 8);
            int kc = (idx % (K / 8)) * 8;
            int g = nbase + row;
            uint4 v = {0u, 0u, 0u, 0u};
            if (g < N) v = *(const uint4*)((const unsigned short*)X + (size_t)g * K + kc);
            *(uint4*)&xs[row][kc] = v;
        }
    }
    constexpr int WROWS = K * NC / 64;
    for (int idx = t; idx < WROWS * 16; idx += 256) {
        int ks = idx >> 4;
        int c4 = (idx & 15) * 4;
        f4 v = *(const f4*)(W + (size_t)ks * 64 + c4);
        int cofs = (NC == 128 && ks >= K) ? 64 : 0;
        int kk = ks & (K - 1);
        #pragma unroll
        for (int j = 0; j < 4; ++j)
            wt[c4 + j + cofs][kk] = f2b(v[j]);
    }
    __syncthreads();

    constexpr int NT = NC / 16;
    f4 acc[NT];
    #pragma unroll
    for (int i = 0; i < NT; ++i) acc[i] = (f4){0.f, 0.f, 0.f, 0.f};

    const int l15 = lane & 15;
    const int kbase = (lane >> 4) * 8;
    #pragma unroll
    for (int kt = 0; kt < K / 32; ++kt) {
        s8v a = *(const s8v*)&xs[wv * 16 + l15][kt * 32 + kbase];
        #pragma unroll
        for (int ct = 0; ct < NT; ++ct) {
            s8v b = *(const s8v*)&wt[ct * 16 + l15][kt * 32 + kbase];
            acc[ct] = __builtin_amdgcn_mfma_f32_16x16x32_bf16(a, b, acc[ct], 0, 0, 0);
        }
    }

    const int r0 = (lane >> 4) * 4;
    #pragma unroll
    for (int r = 0; r < 4; ++r) {
        int g = nbase + wv * 16 + r0 + r;
        if (g >= N) continue;
        float sc = scale ? scale[g] : 1.0f;
        #pragma unroll
        for (int ct = 0; ct < NT; ++ct) {
            int c = ct * 16 + l15;
            float v = acc[ct][r] * sc;
            if (c < 64) {
                if (bias) v += bias[c];
                outA[(size_t)g * 64 + c] = f2b(v);
            } else {
                outB[(size_t)g * 64 + (c - 64)] = f2b(v);
            }
        }
    }
}

// ---------------- gather (bf16 in/out, fp32 accum, 4-deep MLP, optional per-src dis) ----------------
// scale_src=0: out = (g[c] + sum g[r]) * dis[c] + bias
// scale_src=1: out = (g[c]*dis[c] + sum g[r]*dis[r]) * dis[c] + bias
__global__ __launch_bounds__(256) void k_gather(
    const unsigned short* __restrict__ g, const int* __restrict__ rowptr,
    const int* __restrict__ srcs, const float* __restrict__ dis,
    const float* __restrict__ bias, unsigned short* __restrict__ out,
    int N, int do_relu, int scale_src)
{
    int t = blockIdx.x * 256 + threadIdx.x;
    int node = t >> 4;
    if (node >= N) return;
    int c4 = (t & 15) * 4;

    float sc = dis[node];
    f4 a0, a1 = {0.f,0.f,0.f,0.f}, a2 = {0.f,0.f,0.f,0.f}, a3 = {0.f,0.f,0.f,0.f};
    int s = rowptr[node], e = rowptr[node + 1];
    if (scale_src) {
        a0 = ld4(g + (size_t)node * HID + c4) * sc;
        for (; s + 3 < e; s += 4) {
            int r0 = srcs[s], r1 = srcs[s + 1], r2 = srcs[s + 2], r3 = srcs[s + 3];
            a0 += ld4(g + (size_t)r0 * HID + c4) * dis[r0];
            a1 += ld4(g + (size_t)r1 * HID + c4) * dis[r1];
            a2 += ld4(g + (size_t)r2 * HID + c4) * dis[r2];
            a3 += ld4(g + (size_t)r3 * HID + c4) * dis[r3];
        }
        for (; s < e; ++s) { int r0 = srcs[s]; a0 += ld4(g + (size_t)r0 * HID + c4) * dis[r0]; }
    } else {
        a0 = ld4(g + (size_t)node * HID + c4);
        for (; s + 3 < e; s += 4) {
            int r0 = srcs[s], r1 = srcs[s + 1], r2 = srcs[s + 2], r3 = srcs[s + 3];
            a0 += ld4(g + (size_t)r0 * HID + c4);
            a1 += ld4(g + (size_t)r1 * HID + c4);
            a2 += ld4(g + (size_t)r2 * HID + c4);
            a3 += ld4(g + (size_t)r3 * HID + c4);
        }
        for (; s < e; ++s) a0 += ld4(g + (size_t)srcs[s] * HID + c4);
    }
    a0 = (a0 + a1) + (a2 + a3);

    f4 r;
    #pragma unroll
    for (int j = 0; j < 4; ++j) {
        r[j] = a0[j] * sc + bias[c4 + j];
        if (do_relu) r[j] = r[j] > 0.f ? r[j] : 0.f;
    }
    st4(out + (size_t)node * HID + c4, r);
}

// ---------------- fallback path kernels (fp32 VALU GEMM + atomic scatter) ----------------
template<int K, typename TIN, typename TOUT>
__global__ __launch_bounds__(256) void k_gemm(
    const TIN* __restrict__ X, const float* __restrict__ W,
    const float* __restrict__ bias, const float* __restrict__ scale,
    TOUT* __restrict__ out1, TOUT* __restrict__ out2, int N)
{
    __shared__ float xs[64][68];
    __shared__ float ws[64][64];
    const int t = threadIdx.x;
    const int nbase = blockIdx.x * 64;
    const int c4 = (t & 15) * 4;
    const int n4 = (t >> 4) * 4;

    float acc[4][4] = {{0.f,0.f,0.f,0.f},{0.f,0.f,0.f,0.f},{0.f,0.f,0.f,0.f},{0.f,0.f,0.f,0.f}};

    const int node = t & 63;
    const int gn = nbase + node;
    const TIN* Xrow = (gn < N) ? (X + (size_t)gn * K) : nullptr;
    const f4* W4 = (const f4*)W;

    for (int kt = 0; kt < K / 64; ++kt) {
        __syncthreads();
        #pragma unroll
        for (int i = 0; i < 4; ++i) {
            int k4r = i * 4 + (t >> 6);
            f4 v = {0.f, 0.f, 0.f, 0.f};
            if (Xrow) v = ld4(Xrow + (size_t)(kt * 16 + k4r) * 4);
            xs[k4r * 4 + 0][node] = v[0];
            xs[k4r * 4 + 1][node] = v[1];
            xs[k4r * 4 + 2][node] = v[2];
            xs[k4r * 4 + 3][node] = v[3];
        }
        #pragma unroll
        for (int i = 0; i < 4; ++i) {
            int f = i * 256 + t;
            int k = f >> 4, m4 = f & 15;
            *(f4*)&ws[k][m4 * 4] = W4[(size_t)(kt * 64 + k) * 16 + m4];
        }
        __syncthreads();
        #pragma unroll 8
        for (int k = 0; k < 64; ++k) {
            f4 xv = *(const f4*)&xs[k][n4];
            f4 wv = *(const f4*)&ws[k][c4];
            #pragma unroll
            for (int i2 = 0; i2 < 4; ++i2)
                #pragma unroll
                for (int j = 0; j < 4; ++j)
                    acc[i2][j] += xv[i2] * wv[j];
        }
    }

    #pragma unroll
    for (int i = 0; i < 4; ++i) {
        int g = nbase + n4 + i;
        if (g < N) {
            float s = scale ? scale[g] : 1.0f;
            f4 r;
            #pragma unroll
            for (int j = 0; j < 4; ++j) {
                float b = bias ? bias[c4 + j] : 0.0f;
                r[j] = acc[i][j] * s + b;
            }
            st4(out1 + (size_t)g * HID + c4, r);
            if (out2) st4(out2 + (size_t)g * HID + c4, r);
        }
    }
}

template<typename TIN>
__global__ __launch_bounds__(256) void k_gemm2(
    const TIN* __restrict__ X, const float* __restrict__ W,
    const float* __restrict__ bias,
    unsigned short* __restrict__ outA, unsigned short* __restrict__ outB, int N)
{
    __shared__ float xs[64][68];
    __shared__ float ws[64][128];
    const int t = threadIdx.x;
    const int nbase = blockIdx.x * 64;
    const int c4 = (t & 15) * 4;
    const int n4 = (t >> 4) * 4;

    float accA[4][4] = {{0.f,0.f,0.f,0.f},{0.f,0.f,0.f,0.f},{0.f,0.f,0.f,0.f},{0.f,0.f,0.f,0.f}};
    float accB[4][4] = {{0.f,0.f,0.f,0.f},{0.f,0.f,0.f,0.f},{0.f,0.f,0.f,0.f},{0.f,0.f,0.f,0.f}};

    const int node = t & 63;
    const int gn = nbase + node;
    const TIN* Xrow = (gn < N) ? (X + (size_t)gn * HID) : nullptr;
    const f4* W4 = (const f4*)W;

    #pragma unroll
    for (int i = 0; i < 4; ++i) {
        int k4r = i * 4 + (t >> 6);
        f4 v = {0.f, 0.f, 0.f, 0.f};
        if (Xrow) v = ld4(Xrow + (size_t)k4r * 4);
        xs[k4r * 4 + 0][node] = v[0];
        xs[k4r * 4 + 1][node] = v[1];
        xs[k4r * 4 + 2][node] = v[2];
        xs[k4r * 4 + 3][node] = v[3];
    }
    #pragma unroll
    for (int i = 0; i < 8; ++i) {
        int f = i * 256 + t;
        int r = f >> 4, m4 = f & 15;
        int k = r & 63, half = (r >> 6) * 64;
        *(f4*)&ws[k][half + m4 * 4] = W4[f];
    }
    __syncthreads();
    #pragma unroll 8
    for (int k = 0; k < 64; ++k) {
        f4 xv = *(const f4*)&xs[k][n4];
        f4 wa = *(const f4*)&ws[k][c4];
        f4 wb = *(const f4*)&ws[k][64 + c4];
        #pragma unroll
        for (int i2 = 0; i2 < 4; ++i2)
            #pragma unroll
            for (int j = 0; j < 4; ++j) {
                accA[i2][j] += xv[i2] * wa[j];
                accB[i2][j] += xv[i2] * wb[j];
            }
    }

    #pragma unroll
    for (int i = 0; i < 4; ++i) {
        int g = nbase + n4 + i;
        if (g < N) {
            f4 ra, rb;
            #pragma unroll
            for (int j = 0; j < 4; ++j) {
                ra[j] = accA[i][j] + bias[c4 + j];
                rb[j] = accB[i][j];
            }
            st4(outA + (size_t)g * HID + c4, ra);
            st4(outB + (size_t)g * HID + c4, rb);
        }
    }
}

__global__ __launch_bounds__(256) void k_count(const int* __restrict__ col,
                                               float* __restrict__ deg, int E) {
    int e = blockIdx.x * 256 + threadIdx.x;
    if (e < E) unsafeAtomicAdd(&deg[col[e]], 1.0f);
}
__global__ __launch_bounds__(256) void k_initf(float* p, float v, int n) {
    int i = blockIdx.x * 256 + threadIdx.x;
    if (i < n) p[i] = v;
}
__global__ __launch_bounds__(256) void k_rsqrt(float* deg, int N) {
    int i = blockIdx.x * 256 + threadIdx.x;
    if (i < N) deg[i] = rsqrtf(deg[i]);
}
__global__ __launch_bounds__(256) void k_scatter(
    const float* __restrict__ g, const int* __restrict__ row, const int* __restrict__ col,
    float* __restrict__ acc, int E)
{
    int t = blockIdx.x * 256 + threadIdx.x;
    int e = t >> 4;
    if (e >= E) return;
    int c4 = (t & 15) * 4;
    int r = row[e], c = col[e];
    f4 v = *(const f4*)(g + (size_t)r * HID + c4);
    float* dst = acc + (size_t)c * HID + c4;
    unsafeAtomicAdd(dst + 0, v[0]);
    unsafeAtomicAdd(dst + 1, v[1]);
    unsafeAtomicAdd(dst + 2, v[2]);
    unsafeAtomicAdd(dst + 3, v[3]);
}
__global__ __launch_bounds__(256) void k_finish(
    const float* __restrict__ acc, const float* __restrict__ dis, const float* __restrict__ bias,
    float* __restrict__ out, int N, int do_relu)
{
    int t = blockIdx.x * 256 + threadIdx.x;
    if (t >= N * 16) return;
    int node = t >> 4, c4 = (t & 15) * 4;
    float s = dis[node];
    f4 v = *(const f4*)(acc + (size_t)t * 4);
    f4 r;
    #pragma unroll
    for (int j = 0; j < 4; ++j) {
        r[j] = v[j] * s + bias[c4 + j];
        if (do_relu) r[j] = r[j] > 0.f ? r[j] : 0.f;
    }
    *(f4*)(out + (size_t)t * 4) = r;
}

// ---------------- pair scorer: 16 lanes per 2 pairs, 4 row loads in flight ----------------
__global__ __launch_bounds__(256) void k_pair(
    const unsigned short* __restrict__ A, const unsigned short* __restrict__ B,
    const int* __restrict__ pairs, const float* __restrict__ w2, const float* __restrict__ b2,
    float* __restrict__ out, int P)
{
    __shared__ float w2s[64];
    if (threadIdx.x < 64) w2s[threadIdx.x] = w2[threadIdx.x];
    __syncthreads();
    int gidx = blockIdx.x * 256 + threadIdx.x;
    int grp = gidx >> 4;
    int p0 = grp * 2, p1 = p0 + 1;
    if (p0 >= P) return;
    int l = gidx & 15;
    int sub = l & 7;
    int isB = l >> 3;
    const unsigned short* base = isB ? B : A;
    const int* pp = isB ? (pairs + P) : pairs;

    int n0 = pp[p0];
    int4 o0 = *(const int4*)(base + (size_t)n0 * HID + sub * 8);
    bool has1 = (p1 < P);
    int4 o1 = {0, 0, 0, 0};
    if (has1) {
        int n1 = pp[p1];
        o1 = *(const int4*)(base + (size_t)n1 * HID + sub * 8);
    }

    int4 q0, q1;
    q0.x = __shfl_xor(o0.x, 8, 16); q0.y = __shfl_xor(o0.y, 8, 16);
    q0.z = __shfl_xor(o0.z, 8, 16); q0.w = __shfl_xor(o0.w, 8, 16);
    q1.x = __shfl_xor(o1.x, 8, 16); q1.y = __shfl_xor(o1.y, 8, 16);
    q1.z = __shfl_xor(o1.z, 8, 16); q1.w = __shfl_xor(o1.w, 8, 16);

    const float* wv = &w2s[sub * 8];
    int oa0[4] = {o0.x, o0.y, o0.z, o0.w};
    int ob0[4] = {q0.x, q0.y, q0.z, q0.w};
    int oa1[4] = {o1.x, o1.y, o1.z, o1.w};
    int ob1[4] = {q1.x, q1.y, q1.z, q1.w};
    float acc0 = 0.f, acc1 = 0.f;
    #pragma unroll
    for (int k = 0; k < 4; ++k) {
        float alo = __uint_as_float((unsigned)oa0[k] << 16);
        float ahi = __uint_as_float((unsigned)oa0[k] & 0xFFFF0000u);
        float blo = __uint_as_float((unsigned)ob0[k] << 16);
        float bhi = __uint_as_float((unsigned)ob0[k] & 0xFFFF0000u);
        float zlo = alo + blo; zlo = zlo > 0.f ? zlo : 0.f;
        float zhi = ahi + bhi; zhi = zhi > 0.f ? zhi : 0.f;
        acc0 += zlo * wv[2 * k] + zhi * wv[2 * k + 1];

        float clo = __uint_as_float((unsigned)oa1[k] << 16);
        float chi = __uint_as_float((unsigned)oa1[k] & 0xFFFF0000u);
        float dlo = __uint_as_float((unsigned)ob1[k] << 16);
        float dhi = __uint_as_float((unsigned)ob1[k] & 0xFFFF0000u);
        float ylo = clo + dlo; ylo = ylo > 0.f ? ylo : 0.f;
        float yhi = chi + dhi; yhi = yhi > 0.f ? yhi : 0.f;
        acc1 += ylo * wv[2 * k] + yhi * wv[2 * k + 1];
    }
    acc0 += __shfl_xor(acc0, 1, 16);
    acc0 += __shfl_xor(acc0, 2, 16);
    acc0 += __shfl_xor(acc0, 4, 16);
    acc1 += __shfl_xor(acc1, 1, 16);
    acc1 += __shfl_xor(acc1, 2, 16);
    acc1 += __shfl_xor(acc1, 4, 16);
    if (l == 0) {
        float bb = b2[0];
        out[p0] = 1.0f / (1.0f + __expf(-(acc0 + bb)));
        if (has1) out[p1] = 1.0f / (1.0f + __expf(-(acc1 + bb)));
    }
}

extern "C" void kernel_launch(void* const* d_in, const int* in_sizes, int n_in,
                              void* d_out, int out_size, void* d_ws, size_t ws_size,
                              hipStream_t stream)
{
    if (n_in < 11) return;
    const float* x    = (const float*)d_in[0];
    const int*   ei   = (const int*)d_in[1];
    const int*   ep   = (const int*)d_in[2];
    const float* W1   = (const float*)d_in[3];
    const float* b1   = (const float*)d_in[4];
    const float* W2   = (const float*)d_in[5];
    const float* b2   = (const float*)d_in[6];
    const float* lpW1 = (const float*)d_in[7];
    const float* lpb1 = (const float*)d_in[8];
    const float* lpW2 = (const float*)d_in[9];
    const float* lpb2 = (const float*)d_in[10];
    const int N = in_sizes[0] / 128;
    const int E = in_sizes[1] / 2;
    const int P = in_sizes[2] / 2;
    const int* erow = ei;
    const int* ecol = ei + E;
    float* out = (float*)d_out;

    const int gb  = (N + 63) / 64;
    const int gb2 = (N + 127) / 128;              // fused gemm blocks (128 rows)
    const int hb  = (N * 16 + 255) / 256;
    const int NB2 = (N + 511) / 512;
    const int pa  = (E + EPB - 1) / EPB;
    const int pb  = (int)(((size_t)((P + 1) / 2) * 16 + 255) / 256);

    // ---- workspace layout (partition buffer NOT aliased: fused kernel writes both) ----
    char* w = (char*)d_ws;
    float* dis    = (float*)w;  w += (size_t)N * 4;
    int*   rowptr = (int*)w;    w += ((size_t)N + 1) * 4;
    int*   gcur   = (int*)w;    w += 512 * 4;
    int*   srcs   = (int*)w;    w += (size_t)E * 4;
    size_t offb = ((size_t)(w - (char*)d_ws) + 255) & ~(size_t)255;
    unsigned* buf = (unsigned*)((char*)d_ws + offb);
    size_t off = (offb + (size_t)NB2 * CAP2 * 4 + 255) & ~(size_t)255;

    size_t featB = (size_t)N * HID * 2;
    unsigned short* bufA = (unsigned short*)((char*)d_ws + off);
    unsigned short* bufB = bufA + (size_t)N * HID;
    size_t need = off + 2 * featB;

    bool useNew = (N <= 131072) && (NB2 <= 512) && (ws_size >= need) &&
                  ((size_t)E <= 20 * (size_t)N) && (E % 4 == 0);

    if (useNew) {
        // ---- CSR build overlapped with layer-1 GEMM (raw x@W1, scale folded into gather) ----
        k_initcur<<<2, 256, 0, stream>>>(gcur);
        k_fused1<<<pa + gb2, 512, 0, stream>>>(erow, ecol, gcur, buf, E, x, W1, bufA, N, pa);
        k_passC<<<NB2, 512, 0, stream>>>(buf, gcur, rowptr, srcs, dis, N, E, NB2);

        // ---- layer 1 aggregation (per-src dis) ----
        k_gather<<<hb, 256, 0, stream>>>(bufA, rowptr, srcs, dis, b1, bufB, N, 1, 1);
        // ---- layer 2 (MFMA, scale in GEMM) ----
        k_gemmM<64, 64, unsigned short><<<gb, 256, 0, stream>>>(bufB, W2, nullptr, dis, bufA, nullptr, N);
        k_gather<<<hb, 256, 0, stream>>>(bufA, rowptr, srcs, dis, b2, bufB, N, 0, 0);
        // ---- fused link-pred projections (MFMA, dual-output, in-place safe) ----
        k_gemmM<64, 128, unsigned short><<<gb, 256, 0, stream>>>(bufB, lpW1, lpb1, nullptr, bufA, bufB, N);

        k_pair<<<pb, 256, 0, stream>>>(bufA, bufB, ep, lpW2, lpb2, out, P);
    } else {
        // ---- fallback: fp32 VALU + atomic scatter ----
        size_t off_fb = (((size_t)N + 512) * 4 + 255) & ~(size_t)255;
        float* fA = (float*)((char*)d_ws + off_fb);
        float* fB = fA + (size_t)N * HID;
        if (ws_size < off_fb + 2 * (size_t)N * HID * 4) return;
        const int nb = (N + 255) / 256;
        const int eb = (E + 255) / 256;
        const int sb = (int)(((size_t)E * 16 + 255) / 256);
        k_initf<<<nb, 256, 0, stream>>>(dis, 1.0f, N);
        k_count<<<eb, 256, 0, stream>>>(ecol, dis, E);
        k_rsqrt<<<nb, 256, 0, stream>>>(dis, N);
        k_gemm<128, float, float><<<gb, 256, 0, stream>>>(x, W1, nullptr, dis, fA, fB, N);
        k_scatter<<<sb, 256, 0, stream>>>(fA, erow, ecol, fB, E);
        k_finish<<<hb, 256, 0, stream>>>(fB, dis, b1, fB, N, 1);
        k_gemm<64, float, float><<<gb, 256, 0, stream>>>(fB, W2, nullptr, dis, fA, fB, N);
        k_scatter<<<sb, 256, 0, stream>>>(fA, erow, ecol, fB, E);
        k_finish<<<hb, 256, 0, stream>>>(fB, dis, b2, fB, N, 0);
        unsigned short* bA = (unsigned short*)fA;
        unsigned short* bB = bA + (size_t)N * HID;
        k_gemm2<float><<<gb, 256, 0, stream>>>(fB, lpW1, lpb1, bA, bB, N);
        k_pair<<<pb, 256, 0, stream>>>(bA, bB, ep, lpW2, lpb2, out, P);
    }
}